// Round 2
// baseline (428.119 us; speedup 1.0000x reference)
//
#include <hip/hip_runtime.h>

// FWHT-1024 over rows of a (8*8192, 1024) fp32 tensor, fused with
// out = fwht(x)/sqrt(1024) * scale + shift.
//
// One wave (64 lanes) per row; 16 floats/lane in registers.
// Element e = 256*j + 4*lane + r  (j,r in 0..3):
//   h=1,2     : local in r
//   h=4..128  : cross-lane, masks 1..32 on lane index
//   h=256,512 : local in j
//
// Cross-lane traffic rebalanced off the single per-CU DS unit:
//   masks 1,2   -> DPP quad_perm (VALU)                 [0xB1, 0x4E]
//   masks 4,8   -> ds_swizzle imm pattern (DS)          [0x101F, 0x201F]
//   masks 16,32 -> permlane16/32_swap BUILTINS (VALU, gfx950)
// DS ops/wave: 96 -> 32.
//
// Round-1 lesson: raw inline-asm permlane swaps failed (absmax 6.0) —
// gfx950 has a VALU-write -> permlane-read hazard the compiler covers
// with wait states; inside asm blocks that's on us. Builtins fix it.
// The swap butterflies are also written convention-proof: with both
// operands seeded with v, results {d,s} = {own,partner} in SOME order,
// so d+s = own+partner either way, and the upper-lane result
// partner-own = (d+s) - 2*own  =>  fmaf(cm, v, d+s), cm = upper?-2:0.

constexpr int SIZE = 1024;
constexpr float INV_SQRT = 0.03125f; // 1/sqrt(1024)

typedef unsigned int uint2_ev __attribute__((ext_vector_type(2)));

template<int CTRL>
__device__ __forceinline__ float dpp_perm(float x) {
    return __int_as_float(__builtin_amdgcn_update_dpp(
        __float_as_int(x), __float_as_int(x), CTRL, 0xF, 0xF, false));
}

template<int PAT>
__device__ __forceinline__ float lane_swz(float x) {
    return __int_as_float(__builtin_amdgcn_ds_swizzle(__float_as_int(x), PAT));
}

// mask-16 butterfly: result = (lane&16) ? partner-own : own+partner
__device__ __forceinline__ float bfly_swap16(float v, float cm) {
#if __has_builtin(__builtin_amdgcn_permlane16_swap)
    const uint2_ev r = __builtin_amdgcn_permlane16_swap(
        __float_as_uint(v), __float_as_uint(v), false, false);
    const float sum = __uint_as_float(r[0]) + __uint_as_float(r[1]); // own+partner
    return fmaf(cm, v, sum);
#else
    const float o = lane_swz<0x401F>(v);   // xor 16 (within 32-lane half)
    return fmaf(cm, v, v + o);
#endif
}

// mask-32 butterfly
__device__ __forceinline__ float bfly_swap32(float v, float cm) {
#if __has_builtin(__builtin_amdgcn_permlane32_swap)
    const uint2_ev r = __builtin_amdgcn_permlane32_swap(
        __float_as_uint(v), __float_as_uint(v), false, false);
    const float sum = __uint_as_float(r[0]) + __uint_as_float(r[1]); // own+partner
    return fmaf(cm, v, sum);
#else
    const float o = __shfl_xor(v, 32, 64);
    return fmaf(cm, v, v + o);
#endif
}

__global__ __launch_bounds__(256) void fwht1024_kernel(
    const float* __restrict__ x,
    const float* __restrict__ scale,
    const float* __restrict__ shift,
    float* __restrict__ out,
    int nrows)
{
    const int wave = threadIdx.x >> 6;            // 4 waves per block, 1 row each
    const int lane = threadIdx.x & 63;
    const int row  = blockIdx.x * 4 + wave;
    if (row >= nrows) return;

    const float* __restrict__ xr = x + (size_t)row * SIZE;
    float* __restrict__ orow     = out + (size_t)row * SIZE;

    float v[4][4];
    #pragma unroll
    for (int j = 0; j < 4; ++j) {
        const float4 t = *reinterpret_cast<const float4*>(xr + 256 * j + 4 * lane);
        v[j][0] = t.x; v[j][1] = t.y; v[j][2] = t.z; v[j][3] = t.w;
    }

    // h = 1, 2  (within the r quad)
    #pragma unroll
    for (int j = 0; j < 4; ++j) {
        const float a = v[j][0], b = v[j][1], c = v[j][2], d = v[j][3];
        const float ab = a + b, amb = a - b, cd = c + d, cmd = c - d;
        v[j][0] = ab + cd; v[j][1] = amb + cmd;
        v[j][2] = ab - cd; v[j][3] = amb - cmd;
    }

    // butterfly sign constants
    const float s1  = (lane & 1)  ? -1.0f : 1.0f;
    const float s2  = (lane & 2)  ? -1.0f : 1.0f;
    const float s4  = (lane & 4)  ? -1.0f : 1.0f;
    const float s8  = (lane & 8)  ? -1.0f : 1.0f;
    const float c16 = (lane & 16) ? -2.0f : 0.0f;  // convention-proof form
    const float c32 = (lane & 32) ? -2.0f : 0.0f;

    // h = 4  (lane mask 1): DPP quad_perm [1,0,3,2]
    #pragma unroll
    for (int j = 0; j < 4; ++j)
        #pragma unroll
        for (int r = 0; r < 4; ++r) {
            const float o = dpp_perm<0xB1>(v[j][r]);
            v[j][r] = fmaf(s1, v[j][r], o);
        }

    // h = 8  (lane mask 2): DPP quad_perm [2,3,0,1]
    #pragma unroll
    for (int j = 0; j < 4; ++j)
        #pragma unroll
        for (int r = 0; r < 4; ++r) {
            const float o = dpp_perm<0x4E>(v[j][r]);
            v[j][r] = fmaf(s2, v[j][r], o);
        }

    // h = 16 (lane mask 4): ds_swizzle xor=4
    #pragma unroll
    for (int j = 0; j < 4; ++j)
        #pragma unroll
        for (int r = 0; r < 4; ++r) {
            const float o = lane_swz<0x101F>(v[j][r]);
            v[j][r] = fmaf(s4, v[j][r], o);
        }

    // h = 32 (lane mask 8): ds_swizzle xor=8
    #pragma unroll
    for (int j = 0; j < 4; ++j)
        #pragma unroll
        for (int r = 0; r < 4; ++r) {
            const float o = lane_swz<0x201F>(v[j][r]);
            v[j][r] = fmaf(s8, v[j][r], o);
        }

    // h = 64 (lane mask 16): permlane16_swap (VALU)
    #pragma unroll
    for (int j = 0; j < 4; ++j)
        #pragma unroll
        for (int r = 0; r < 4; ++r)
            v[j][r] = bfly_swap16(v[j][r], c16);

    // h = 128 (lane mask 32): permlane32_swap (VALU)
    #pragma unroll
    for (int j = 0; j < 4; ++j)
        #pragma unroll
        for (int r = 0; r < 4; ++r)
            v[j][r] = bfly_swap32(v[j][r], c32);

    // h = 256, 512  (within the j quad)
    #pragma unroll
    for (int r = 0; r < 4; ++r) {
        const float a = v[0][r], b = v[1][r], c = v[2][r], d = v[3][r];
        const float ab = a + b, amb = a - b, cd = c + d, cmd = c - d;
        v[0][r] = ab + cd; v[1][r] = amb + cmd;
        v[2][r] = ab - cd; v[3][r] = amb - cmd;
    }

    // epilogue: *1/32, scale, shift; coalesced float4 stores
    #pragma unroll
    for (int j = 0; j < 4; ++j) {
        const int base = 256 * j + 4 * lane;
        const float4 sc = *reinterpret_cast<const float4*>(scale + base);
        const float4 sh = *reinterpret_cast<const float4*>(shift + base);
        float4 o;
        o.x = fmaf(v[j][0] * INV_SQRT, sc.x, sh.x);
        o.y = fmaf(v[j][1] * INV_SQRT, sc.y, sh.y);
        o.z = fmaf(v[j][2] * INV_SQRT, sc.z, sh.z);
        o.w = fmaf(v[j][3] * INV_SQRT, sc.w, sh.w);
        *reinterpret_cast<float4*>(orow + base) = o;
    }
}

extern "C" void kernel_launch(void* const* d_in, const int* in_sizes, int n_in,
                              void* d_out, int out_size, void* d_ws, size_t ws_size,
                              hipStream_t stream)
{
    const float* x     = (const float*)d_in[0];
    const float* scale = (const float*)d_in[1];
    const float* shift = (const float*)d_in[2];
    float* out         = (float*)d_out;

    const int nrows = in_sizes[0] / SIZE;        // 65536
    const int blocks = (nrows + 3) / 4;          // 4 rows (waves) per block

    fwht1024_kernel<<<blocks, 256, 0, stream>>>(x, scale, shift, out, nrows);
}

// Round 4
// 418.239 us; speedup vs baseline: 1.0236x; 1.0236x over previous
//
#include <hip/hip_runtime.h>

// FWHT-1024 over rows of a (8*8192, 1024) fp32 tensor, fused with
// out = fwht(x)/sqrt(1024) * scale + shift.
//
// One wave (64 lanes) per row; 16 floats/lane in registers.
// Element e = 256*j + 4*lane + r  (j,r in 0..3):
//   h=1,2     : local in r
//   h=4..128  : cross-lane, masks 1..32 on lane index
//   h=256,512 : local in j
//
// Round-2 finding: kernel is PURELY memory-bound (~97us for 537MB =
// 5.5 TB/s, 88% of copy ceiling; VALU+DS < 5% of cycle budget).
// Lever: x read once, out written once -> non-temporal ('nt') loads/
// stores keep the streams from thrashing L2. scale/shift (8KB, reused
// by all 65536 waves) stay cached.
// Round-3 fix: __builtin_nontemporal_* rejects HIP_vector_type float4
// (struct). Use a clang ext_vector_type(4) float instead — same 16B
// dwordx4 access, builtin-compatible.

constexpr int SIZE = 1024;
constexpr float INV_SQRT = 0.03125f; // 1/sqrt(1024)

typedef unsigned int uint2_ev __attribute__((ext_vector_type(2)));
typedef float        f32x4   __attribute__((ext_vector_type(4)));

template<int CTRL>
__device__ __forceinline__ float dpp_perm(float x) {
    return __int_as_float(__builtin_amdgcn_update_dpp(
        __float_as_int(x), __float_as_int(x), CTRL, 0xF, 0xF, false));
}

template<int PAT>
__device__ __forceinline__ float lane_swz(float x) {
    return __int_as_float(__builtin_amdgcn_ds_swizzle(__float_as_int(x), PAT));
}

// mask-16 butterfly: result = (lane&16) ? partner-own : own+partner
// (convention-proof: both swap outputs summed, upper lanes subtract 2*own)
__device__ __forceinline__ float bfly_swap16(float v, float cm) {
#if __has_builtin(__builtin_amdgcn_permlane16_swap)
    const uint2_ev r = __builtin_amdgcn_permlane16_swap(
        __float_as_uint(v), __float_as_uint(v), false, false);
    const float sum = __uint_as_float(r[0]) + __uint_as_float(r[1]);
    return fmaf(cm, v, sum);
#else
    const float o = lane_swz<0x401F>(v);
    return fmaf(cm, v, v + o);
#endif
}

__device__ __forceinline__ float bfly_swap32(float v, float cm) {
#if __has_builtin(__builtin_amdgcn_permlane32_swap)
    const uint2_ev r = __builtin_amdgcn_permlane32_swap(
        __float_as_uint(v), __float_as_uint(v), false, false);
    const float sum = __uint_as_float(r[0]) + __uint_as_float(r[1]);
    return fmaf(cm, v, sum);
#else
    const float o = __shfl_xor(v, 32, 64);
    return fmaf(cm, v, v + o);
#endif
}

__global__ __launch_bounds__(256) void fwht1024_kernel(
    const float* __restrict__ x,
    const float* __restrict__ scale,
    const float* __restrict__ shift,
    float* __restrict__ out,
    int nrows)
{
    const int wave = threadIdx.x >> 6;            // 4 waves per block, 1 row each
    const int lane = threadIdx.x & 63;
    const int row  = blockIdx.x * 4 + wave;
    if (row >= nrows) return;

    const float* __restrict__ xr = x + (size_t)row * SIZE;
    float* __restrict__ orow     = out + (size_t)row * SIZE;

    // streaming loads: x is touched exactly once -> 'nt' bypasses L2 LRU
    float v[4][4];
    #pragma unroll
    for (int j = 0; j < 4; ++j) {
        const f32x4 t = __builtin_nontemporal_load(
            reinterpret_cast<const f32x4*>(xr + 256 * j + 4 * lane));
        v[j][0] = t.x; v[j][1] = t.y; v[j][2] = t.z; v[j][3] = t.w;
    }

    // h = 1, 2  (within the r quad)
    #pragma unroll
    for (int j = 0; j < 4; ++j) {
        const float a = v[j][0], b = v[j][1], c = v[j][2], d = v[j][3];
        const float ab = a + b, amb = a - b, cd = c + d, cmd = c - d;
        v[j][0] = ab + cd; v[j][1] = amb + cmd;
        v[j][2] = ab - cd; v[j][3] = amb - cmd;
    }

    // butterfly sign constants
    const float s1  = (lane & 1)  ? -1.0f : 1.0f;
    const float s2  = (lane & 2)  ? -1.0f : 1.0f;
    const float s4  = (lane & 4)  ? -1.0f : 1.0f;
    const float s8  = (lane & 8)  ? -1.0f : 1.0f;
    const float c16 = (lane & 16) ? -2.0f : 0.0f;
    const float c32 = (lane & 32) ? -2.0f : 0.0f;

    // h = 4  (lane mask 1): DPP quad_perm [1,0,3,2]
    #pragma unroll
    for (int j = 0; j < 4; ++j)
        #pragma unroll
        for (int r = 0; r < 4; ++r) {
            const float o = dpp_perm<0xB1>(v[j][r]);
            v[j][r] = fmaf(s1, v[j][r], o);
        }

    // h = 8  (lane mask 2): DPP quad_perm [2,3,0,1]
    #pragma unroll
    for (int j = 0; j < 4; ++j)
        #pragma unroll
        for (int r = 0; r < 4; ++r) {
            const float o = dpp_perm<0x4E>(v[j][r]);
            v[j][r] = fmaf(s2, v[j][r], o);
        }

    // h = 16 (lane mask 4): ds_swizzle xor=4
    #pragma unroll
    for (int j = 0; j < 4; ++j)
        #pragma unroll
        for (int r = 0; r < 4; ++r) {
            const float o = lane_swz<0x101F>(v[j][r]);
            v[j][r] = fmaf(s4, v[j][r], o);
        }

    // h = 32 (lane mask 8): ds_swizzle xor=8
    #pragma unroll
    for (int j = 0; j < 4; ++j)
        #pragma unroll
        for (int r = 0; r < 4; ++r) {
            const float o = lane_swz<0x201F>(v[j][r]);
            v[j][r] = fmaf(s8, v[j][r], o);
        }

    // h = 64 (lane mask 16): permlane16_swap (VALU)
    #pragma unroll
    for (int j = 0; j < 4; ++j)
        #pragma unroll
        for (int r = 0; r < 4; ++r)
            v[j][r] = bfly_swap16(v[j][r], c16);

    // h = 128 (lane mask 32): permlane32_swap (VALU)
    #pragma unroll
    for (int j = 0; j < 4; ++j)
        #pragma unroll
        for (int r = 0; r < 4; ++r)
            v[j][r] = bfly_swap32(v[j][r], c32);

    // h = 256, 512  (within the j quad)
    #pragma unroll
    for (int r = 0; r < 4; ++r) {
        const float a = v[0][r], b = v[1][r], c = v[2][r], d = v[3][r];
        const float ab = a + b, amb = a - b, cd = c + d, cmd = c - d;
        v[0][r] = ab + cd; v[1][r] = amb + cmd;
        v[2][r] = ab - cd; v[3][r] = amb - cmd;
    }

    // epilogue: *1/32, scale, shift (cached — reused by all waves);
    // non-temporal coalesced stores (out never re-read)
    #pragma unroll
    for (int j = 0; j < 4; ++j) {
        const int base = 256 * j + 4 * lane;
        const float4 sc = *reinterpret_cast<const float4*>(scale + base);
        const float4 sh = *reinterpret_cast<const float4*>(shift + base);
        f32x4 o;
        o.x = fmaf(v[j][0] * INV_SQRT, sc.x, sh.x);
        o.y = fmaf(v[j][1] * INV_SQRT, sc.y, sh.y);
        o.z = fmaf(v[j][2] * INV_SQRT, sc.z, sh.z);
        o.w = fmaf(v[j][3] * INV_SQRT, sc.w, sh.w);
        __builtin_nontemporal_store(o, reinterpret_cast<f32x4*>(orow + base));
    }
}

extern "C" void kernel_launch(void* const* d_in, const int* in_sizes, int n_in,
                              void* d_out, int out_size, void* d_ws, size_t ws_size,
                              hipStream_t stream)
{
    const float* x     = (const float*)d_in[0];
    const float* scale = (const float*)d_in[1];
    const float* shift = (const float*)d_in[2];
    float* out         = (float*)d_out;

    const int nrows = in_sizes[0] / SIZE;        // 65536
    const int blocks = (nrows + 3) / 4;          // 4 rows (waves) per block

    fwht1024_kernel<<<blocks, 256, 0, stream>>>(x, scale, shift, out, nrows);
}